// Round 6
// baseline (154.152 us; speedup 1.0000x reference)
//
#include <hip/hip_runtime.h>

typedef _Float16 half8 __attribute__((ext_vector_type(8)));
typedef _Float16 half2v __attribute__((ext_vector_type(2)));
typedef float floatx4 __attribute__((ext_vector_type(4)));

#define IN_DIM 256
#define OUT_DIM 256
#define M_TILE 32
#define ROWB 288  // bytes per LDS row: 256 + 32 pad -> row starts 8 dwords apart (mod 32 banks)
                  // => ds_read_b64 B-frag access is exactly conflict-free (4 dwords/bank)

// Quantize weight -> f16 in MFMA-A-fragment-permuted order:
//   perm[((ct*8 + ks)*64 + lane)*8 + e] = rne(W[ct*16 + (lane&15)][ks*32 + (lane>>4)*8 + e] * 100)
// so the gemm's A-frag load for (col-tile ct, k-step ks) is one fully-coalesced
// 16B/lane global_load_dwordx4. Also quantizes bias and writes the scalar output.
__global__ void quant_kernel(const float* __restrict__ w,
                             const float* __restrict__ bias,
                             const float* __restrict__ in_scale,
                             _Float16* __restrict__ wqp,
                             float* __restrict__ bq,
                             float* __restrict__ out_scalar) {
    int t = blockIdx.x * blockDim.x + threadIdx.x;   // 8192 threads, 8 elems each
    if (t < (OUT_DIM * IN_DIM) / 8) {
        int lane = t & 63;
        int ks   = (t >> 6) & 7;
        int ct   = t >> 9;
        int row  = ct * 16 + (lane & 15);
        int k0   = ks * 32 + (lane >> 4) * 8;
        const float* src = w + row * IN_DIM + k0;    // 32B contiguous per thread
        half8 h;
#pragma unroll
        for (int e = 0; e < 8; ++e)
            h[e] = (_Float16)rintf(src[e] * 100.0f); // jnp.round = round-half-even
        *((half8*)wqp + t) = h;
    }
    if (t < OUT_DIM) {
        float s2 = in_scale[0] * 100.0f;
        bq[t] = rintf(bias[t] * s2);
    }
    if (t == 0 && out_scalar != nullptr)
        out_scalar[0] = in_scale[0] * 100.0f;
}

// u8 bytes (cx values < 200) -> 8 exact f16 via exponent-bias trick:
// f16 bits (0x6400 | v) == 1024.0 + v exactly for v in [0,1024); subtract 1024.
__device__ __forceinline__ half2v u8pair_to_h2(unsigned src, unsigned sel) {
    unsigned d = __builtin_amdgcn_perm(0x64646464u, src, sel);
    half2v h = __builtin_bit_cast(half2v, d);
    return h - (_Float16)1024.0f;           // v_pk_add_f16 with -1024,-1024
}

__device__ __forceinline__ half8 u8x8_to_h8(uint2 u) {
    half2v h0 = u8pair_to_h2(u.x, 0x05010400u);  // bytes b1,b0
    half2v h1 = u8pair_to_h2(u.x, 0x05030402u);  // bytes b3,b2
    half2v h2 = u8pair_to_h2(u.y, 0x05010400u);
    half2v h3 = u8pair_to_h2(u.y, 0x05030402u);
    half8 r;
    r[0] = h0[0]; r[1] = h0[1]; r[2] = h1[0]; r[3] = h1[1];
    r[4] = h2[0]; r[5] = h2[1]; r[6] = h3[0]; r[7] = h3[1];
    return r;
}

// M_TILE=32, cx staged as uint8 (values < 200 by construction): 9.2 KB LDS/block,
// grid 2048, 8 blocks/CU = 32 waves/CU (100% of slots). 8 independent blocks per CU
// at staggered phases = natural 8-deep pipeline across stage/compute/store.
// A = W (permuted, coalesced 16B/lane, L2-hit). D: row(quad*4+reg)=out col,
// col(lane&15)=batch row -> float4 plain stores (best WRITE_SIZE, per R0 vs R3).
__global__ __launch_bounds__(256, 8) void gemm_kernel(const int* __restrict__ cx,
                                                      const _Float16* __restrict__ wqp,
                                                      const float* __restrict__ bq,
                                                      float* __restrict__ out) {
    __shared__ unsigned char cB[M_TILE * ROWB];   // 9216 B

    const int t = threadIdx.x;
    const size_t m0 = (size_t)blockIdx.x * M_TILE;

    // ---- stage 32 rows x 256 int32 -> u8, coalesced int4 loads ----
    const int* cbase = cx + m0 * IN_DIM;
#pragma unroll
    for (int i = 0; i < 8; ++i) {
        int flat = i * 1024 + t * 4;              // element index
        int4 v = *(const int4*)(cbase + flat);
        unsigned pk = (unsigned)v.x | ((unsigned)v.y << 8) |
                      ((unsigned)v.z << 16) | ((unsigned)v.w << 24);
        int row = flat >> 8;
        int col = flat & 255;
        *(unsigned*)&cB[row * ROWB + col] = pk;   // lanes -> consecutive banks, 2-way (free)
    }
    __syncthreads();

    const int wave = t >> 6;
    const int lane = t & 63;
    const int m16  = lane & 15;
    const int quad = lane >> 4;

    floatx4 acc[4][2] = {};   // [i: out-col tile][j: batch-row tile]

    const half8* wbase = (const half8*)wqp;   // units of 16B
#pragma unroll
    for (int ks = 0; ks < 8; ++ks) {
        const int kb = ks * 32 + quad * 8;    // byte offset within row
        half8 bfr[2];
#pragma unroll
        for (int j = 0; j < 2; ++j) {         // ds_read_b64, conflict-free (ROWB=288)
            uint2 u = *(const uint2*)&cB[(j * 16 + m16) * ROWB + kb];
            bfr[j] = u8x8_to_h8(u);
        }
#pragma unroll
        for (int i = 0; i < 4; ++i) {
            half8 afr = wbase[((wave * 4 + i) * 8 + ks) * 64 + lane];
#pragma unroll
            for (int j = 0; j < 2; ++j)
                acc[i][j] = __builtin_amdgcn_mfma_f32_16x16x32_f16(afr, bfr[j], acc[i][j], 0, 0, 0);
        }
    }

    // ---- epilogue: lane owns 4 consecutive out cols -> float4 stores ----
#pragma unroll
    for (int i = 0; i < 4; ++i) {
        int col = wave * 64 + i * 16 + quad * 4;
        floatx4 bv = *(const floatx4*)(bq + col);
#pragma unroll
        for (int j = 0; j < 2; ++j) {
            size_t row = m0 + j * 16 + m16;
            floatx4 v = acc[i][j] + bv;
            *(floatx4*)(out + row * OUT_DIM + col) = v;
        }
    }
}

extern "C" void kernel_launch(void* const* d_in, const int* in_sizes, int n_in,
                              void* d_out, int out_size, void* d_ws, size_t ws_size,
                              hipStream_t stream) {
    const int*   cx       = (const int*)d_in[0];
    const float* w        = (const float*)d_in[1];
    const float* bias     = (const float*)d_in[2];
    const float* in_scale = (const float*)d_in[3];
    float* out = (float*)d_out;

    _Float16* wqp = (_Float16*)d_ws;                              // 128 KB, permuted
    float*    bq  = (float*)((char*)d_ws + OUT_DIM * IN_DIM * 2); // 1 KB

    const int rows = in_sizes[0] / IN_DIM;          // 65536
    const size_t gemm_elems = (size_t)rows * OUT_DIM;
    float* out_scalar = ((size_t)out_size > gemm_elems) ? (out + gemm_elems) : nullptr;

    quant_kernel<<<32, 256, 0, stream>>>(w, bias, in_scale, wqp, bq, out_scalar);
    gemm_kernel<<<rows / M_TILE, 256, 0, stream>>>(cx, wqp, bq, out);
}

// Round 7
// 142.374 us; speedup vs baseline: 1.0827x; 1.0827x over previous
//
#include <hip/hip_runtime.h>

typedef _Float16 half8 __attribute__((ext_vector_type(8)));
typedef _Float16 half4 __attribute__((ext_vector_type(4)));
typedef float floatx4 __attribute__((ext_vector_type(4)));

#define IN_DIM 256
#define OUT_DIM 256
#define ROWSTR 264  // f16 per LDS row incl pad (proven bank pattern from R0)

// Quantize weight -> f16 in MFMA-A-fragment-permuted order:
//   perm[((ct*8 + ks)*64 + lane)*8 + e] = rne(W[ct*16 + (lane&15)][ks*32 + (lane>>4)*8 + e] * 100)
// so the gemm's A-frag load for (col-tile ct, k-step ks) is one fully-coalesced
// 16B/lane global_load_dwordx4. Also quantizes bias and writes the scalar output.
__global__ void quant_kernel(const float* __restrict__ w,
                             const float* __restrict__ bias,
                             const float* __restrict__ in_scale,
                             _Float16* __restrict__ wqp,
                             float* __restrict__ bq,
                             float* __restrict__ out_scalar) {
    int t = blockIdx.x * blockDim.x + threadIdx.x;   // 8192 threads, 8 elems each
    if (t < (OUT_DIM * IN_DIM) / 8) {
        int lane = t & 63;
        int ks   = (t >> 6) & 7;
        int ct   = t >> 9;
        int row  = ct * 16 + (lane & 15);
        int k0   = ks * 32 + (lane >> 4) * 8;
        const float* src = w + row * IN_DIM + k0;    // 32B contiguous per thread
        half8 h;
#pragma unroll
        for (int e = 0; e < 8; ++e)
            h[e] = (_Float16)rintf(src[e] * 100.0f); // jnp.round = round-half-even
        *((half8*)wqp + t) = h;
    }
    if (t < OUT_DIM) {
        float s2 = in_scale[0] * 100.0f;
        bq[t] = rintf(bias[t] * s2);
    }
    if (t == 0 && out_scalar != nullptr)
        out_scalar[0] = in_scale[0] * 100.0f;
}

// Barrier-free wave-autonomous gemm. Each WAVE owns 16 batch rows x 256 out cols:
//  - stages its own 16 rows (int32 -> f16) into a wave-private LDS slice (8.4 KB)
//  - NO __syncthreads anywhere: producer wave == consumer wave, so only its own
//    vmcnt/lgkmcnt orderings apply; waves free-run and drift apart, interleaving
//    the HBM read burst / MFMA / HBM write burst across the 16 resident waves/CU
//    instead of executing them in machine-wide lockstep (R0's limiter).
//  - computes in two 128-col passes (acc = 8 floatx4 = 32 VGPR); the stores of
//    pass 0 drain under the MFMAs of pass 1.
// A-frags (wqp) are the same addresses for every wave -> L1/L2 broadcast; working
// set per k-step is 8 KB (L1-resident). D: row(quad*4+reg)=out col, col(lane&15)=
// batch row -> float4 stores, 512 B contiguous per row per pass (R0's pattern).
__global__ __launch_bounds__(256, 4) void gemm_kernel(const int* __restrict__ cx,
                                                      const _Float16* __restrict__ wqp,
                                                      const float* __restrict__ bq,
                                                      float* __restrict__ out) {
    __shared__ _Float16 cT[4 * 16 * ROWSTR];   // 4 wave-private slices, 33792 B total

    const int t    = threadIdx.x;
    const int wave = t >> 6;
    const int lane = t & 63;
    const int m16  = lane & 15;
    const int quad = lane >> 4;

    const size_t r0 = ((size_t)blockIdx.x * 4 + wave) * 16;   // this wave's 16 rows
    _Float16* slice = &cT[wave * 16 * ROWSTR];

    // ---- stage 16 rows x 256 int32 -> f16, wave-private, fully coalesced ----
    const int* cbase = cx + r0 * IN_DIM;
#pragma unroll
    for (int i = 0; i < 16; ++i) {
        int4 v = *(const int4*)(cbase + i * 256 + lane * 4);  // one full row per iter
        half4 h;
        h.x = (_Float16)v.x; h.y = (_Float16)v.y;
        h.z = (_Float16)v.z; h.w = (_Float16)v.w;
        *(half4*)&slice[i * ROWSTR + lane * 4] = h;
    }
    // (no barrier)

    const half8* wbase = (const half8*)wqp;   // units of 16B

#pragma unroll
    for (int h = 0; h < 2; ++h) {             // two 128-col passes
        floatx4 acc[8] = {};
#pragma unroll
        for (int ks = 0; ks < 8; ++ks) {
            const int kb = ks * 32 + quad * 8;
            half8 bfr = *(const half8*)&slice[m16 * ROWSTR + kb];  // reused by 8 MFMAs
#pragma unroll
            for (int i = 0; i < 8; ++i) {
                half8 afr = wbase[(((h * 8 + i) * 8) + ks) * 64 + lane];  // L1/L2 broadcast
                acc[i] = __builtin_amdgcn_mfma_f32_16x16x32_f16(afr, bfr, acc[i], 0, 0, 0);
            }
        }
        // ---- epilogue for this half: 512 B contiguous per row ----
#pragma unroll
        for (int i = 0; i < 8; ++i) {
            int col = (h * 8 + i) * 16 + quad * 4;
            floatx4 bv = *(const floatx4*)(bq + col);
            floatx4 v = acc[i] + bv;
            *(floatx4*)(out + (r0 + m16) * OUT_DIM + col) = v;
        }
    }
}

extern "C" void kernel_launch(void* const* d_in, const int* in_sizes, int n_in,
                              void* d_out, int out_size, void* d_ws, size_t ws_size,
                              hipStream_t stream) {
    const int*   cx       = (const int*)d_in[0];
    const float* w        = (const float*)d_in[1];
    const float* bias     = (const float*)d_in[2];
    const float* in_scale = (const float*)d_in[3];
    float* out = (float*)d_out;

    _Float16* wqp = (_Float16*)d_ws;                              // 128 KB, permuted
    float*    bq  = (float*)((char*)d_ws + OUT_DIM * IN_DIM * 2); // 1 KB

    const int rows = in_sizes[0] / IN_DIM;          // 65536
    const size_t gemm_elems = (size_t)rows * OUT_DIM;
    float* out_scalar = ((size_t)out_size > gemm_elems) ? (out + gemm_elems) : nullptr;

    quant_kernel<<<32, 256, 0, stream>>>(w, bias, in_scale, wqp, bq, out_scalar);
    gemm_kernel<<<rows / 64, 256, 0, stream>>>(cx, wqp, bq, out);   // 64 rows per block (16/wave)
}

// Round 8
// 137.291 us; speedup vs baseline: 1.1228x; 1.0370x over previous
//
#include <hip/hip_runtime.h>

typedef _Float16 half8 __attribute__((ext_vector_type(8)));
typedef float floatx4 __attribute__((ext_vector_type(4)));

#define IN_DIM 256
#define OUT_DIM 256
#define M_TILE 64
#define GRID 256   // 1 block/CU (128 KB LDS); each block streams ntiles/GRID tiles

// Quantize weight -> f16 in MFMA-A-fragment-permuted order:
//   perm[((ct*8 + ks)*64 + lane)*8 + e] = rne(W[ct*16 + (lane&15)][ks*32 + (lane>>4)*8 + e] * 100)
// Bias is quantized AND gets the -1024*rowsum(Wq) fold: the gemm feeds B-values as
// (1024 + x) via the f16 exponent-bias trick, so sum_k Wq*(1024+x) needs the
// 1024*sum_k Wq correction folded here (exact: |rowsum| < 2^14, all ints < 2^24).
__global__ void quant_kernel(const float* __restrict__ w,
                             const float* __restrict__ bias,
                             const float* __restrict__ in_scale,
                             _Float16* __restrict__ wqp,
                             float* __restrict__ bq,
                             float* __restrict__ out_scalar) {
    int t = blockIdx.x * blockDim.x + threadIdx.x;   // 8192 threads, 8 elems each
    if (t < (OUT_DIM * IN_DIM) / 8) {
        int lane = t & 63;
        int ks   = (t >> 6) & 7;
        int ct   = t >> 9;
        int row  = ct * 16 + (lane & 15);
        int k0   = ks * 32 + (lane >> 4) * 8;
        const float* src = w + row * IN_DIM + k0;    // 32B contiguous per thread
        half8 h;
#pragma unroll
        for (int e = 0; e < 8; ++e)
            h[e] = (_Float16)rintf(src[e] * 100.0f); // jnp.round = round-half-even
        *((half8*)wqp + t) = h;
    }
    if (t < OUT_DIM) {
        float s2 = in_scale[0] * 100.0f;
        const float* wr = w + t * IN_DIM;
        float rs = 0.0f;                             // rowsum of quantized weights (exact ints)
        for (int k = 0; k < IN_DIM; ++k)
            rs += rintf(wr[k] * 100.0f);
        bq[t] = rintf(bias[t] * s2) - 1024.0f * rs;  // fold the +1024 B-offset correction
    }
    if (t == 0 && out_scalar != nullptr)
        out_scalar[0] = in_scale[0] * 100.0f;
}

// Persistent 2-deep pipelined gemm. grid=256 (1 block/CU), each block streams 4 tiles:
//  - W fragments live ENTIRELY in registers (32 half8 = 128 VGPR/wave), loaded once.
//  - B (c_x) staged raw int32 via global_load_lds (async DMA, 16B/lane) into a
//    128 KB double buffer; stage(t+1) issued BEFORE compute(t) so next-tile reads
//    and current-tile writes ride the bus under the MFMAs (T3 2-phase pipeline).
//  - global_load_lds writes linearly, so bank conflicts on the 1024B-stride rows
//    are fixed by SOURCE-side XOR swizzle: LDS 16B-chunk c holds global chunk
//    c ^ (row&7); the read applies the same involution. Still fully coalesced
//    (permutation stays within each 128B window).
//  - int32 -> f16 on read: (0x6400 | v) = 1024+v exactly (v < 256); the -1024 is
//    folded into bq by quant_kernel. 2 VALU (v_perm + v_or) per f16 pair.
// D layout: row(quad*4+reg)=out col, col(lane&15)=batch row -> float4 stores.
__global__ __launch_bounds__(256, 1) void gemm_kernel(const int* __restrict__ cx,
                                                      const _Float16* __restrict__ wqp,
                                                      const float* __restrict__ bq,
                                                      float* __restrict__ out,
                                                      int ntiles) {
    __shared__ int buf[2][M_TILE * IN_DIM];   // 2 x 64 KB

    const int t    = threadIdx.x;
    const int wave = t >> 6;
    const int lane = t & 63;
    const int m16  = lane & 15;
    const int quad = lane >> 4;
    const int bid  = blockIdx.x;

    // ---- hoist all A-fragments for this wave's 64 out-cols: tile-invariant ----
    const half8* wbase = (const half8*)wqp;   // units of 16B
    half8 A[4][8];
#pragma unroll
    for (int i = 0; i < 4; ++i)
#pragma unroll
        for (int ks = 0; ks < 8; ++ks)
            A[i][ks] = wbase[((wave * 4 + i) * 8 + ks) * 64 + lane];

    // ---- prologue: stage tile 'bid' into buf[0] ----
    {
        const size_t base = (size_t)bid * M_TILE * IN_DIM;
#pragma unroll
        for (int i = 0; i < 16; ++i) {
            int r = wave * 16 + i;
            const int* g = cx + base + (size_t)r * IN_DIM + ((lane ^ (i & 7)) << 2);
            __builtin_amdgcn_global_load_lds(
                (const __attribute__((address_space(1))) void*)g,
                (__attribute__((address_space(3))) void*)&buf[0][r * IN_DIM],
                16, 0, 0);
        }
    }
    __syncthreads();

    int cur = 0;
    for (int tile = bid; tile < ntiles; tile += GRID) {
        // ---- stage next tile into the other buffer (issued before compute) ----
        const int nxt = tile + GRID;
        if (nxt < ntiles) {
            const size_t base = (size_t)nxt * M_TILE * IN_DIM;
#pragma unroll
            for (int i = 0; i < 16; ++i) {
                int r = wave * 16 + i;
                const int* g = cx + base + (size_t)r * IN_DIM + ((lane ^ (i & 7)) << 2);
                __builtin_amdgcn_global_load_lds(
                    (const __attribute__((address_space(1))) void*)g,
                    (__attribute__((address_space(3))) void*)&buf[cur ^ 1][r * IN_DIM],
                    16, 0, 0);
            }
        }

        // ---- compute from buf[cur] ----
        const int* B = &buf[cur][0];
        floatx4 acc[4][4] = {};
#pragma unroll
        for (int ks = 0; ks < 8; ++ks) {
            half8 bfr[4];
#pragma unroll
            for (int j = 0; j < 4; ++j) {
                int r  = j * 16 + m16;
                int c0 = ks * 8 + quad * 2;     // 16B-chunk index within the row
                int x  = m16 & 7;               // source-swizzle involution key
                uint4 a  = *(const uint4*)&B[r * IN_DIM + (((c0    ) ^ x) << 2)];
                uint4 b2 = *(const uint4*)&B[r * IN_DIM + (((c0 + 1) ^ x) << 2)];
                uint4 p;
                p.x = __builtin_amdgcn_perm(a.y,  a.x,  0x05040100u) | 0x64006400u;
                p.y = __builtin_amdgcn_perm(a.w,  a.z,  0x05040100u) | 0x64006400u;
                p.z = __builtin_amdgcn_perm(b2.y, b2.x, 0x05040100u) | 0x64006400u;
                p.w = __builtin_amdgcn_perm(b2.w, b2.z, 0x05040100u) | 0x64006400u;
                bfr[j] = __builtin_bit_cast(half8, p);  // f16 values 1024 + x[k]
            }
#pragma unroll
            for (int i = 0; i < 4; ++i)
#pragma unroll
                for (int j = 0; j < 4; ++j)
                    acc[i][j] = __builtin_amdgcn_mfma_f32_16x16x32_f16(A[i][ks], bfr[j], acc[i][j], 0, 0, 0);
        }

        // ---- store: lane owns 4 consecutive out cols -> float4 stores ----
        const size_t m0 = (size_t)tile * M_TILE;
#pragma unroll
        for (int i = 0; i < 4; ++i) {
            int col = wave * 64 + i * 16 + quad * 4;
            floatx4 bv = *(const floatx4*)(bq + col);   // bias incl. -1024*rowsum fold
#pragma unroll
            for (int j = 0; j < 4; ++j) {
                size_t row = m0 + j * 16 + m16;
                floatx4 v = acc[i][j] + bv;
                *(floatx4*)(out + row * OUT_DIM + col) = v;
            }
        }

        __syncthreads();   // drains stage (had full compute to land) + stores (L2-fast)
        cur ^= 1;
    }
}

extern "C" void kernel_launch(void* const* d_in, const int* in_sizes, int n_in,
                              void* d_out, int out_size, void* d_ws, size_t ws_size,
                              hipStream_t stream) {
    const int*   cx       = (const int*)d_in[0];
    const float* w        = (const float*)d_in[1];
    const float* bias     = (const float*)d_in[2];
    const float* in_scale = (const float*)d_in[3];
    float* out = (float*)d_out;

    _Float16* wqp = (_Float16*)d_ws;                              // 128 KB, permuted
    float*    bq  = (float*)((char*)d_ws + OUT_DIM * IN_DIM * 2); // 1 KB

    const int rows = in_sizes[0] / IN_DIM;          // 65536
    const size_t gemm_elems = (size_t)rows * OUT_DIM;
    float* out_scalar = ((size_t)out_size > gemm_elems) ? (out + gemm_elems) : nullptr;

    const int ntiles = rows / M_TILE;               // 1024
    quant_kernel<<<32, 256, 0, stream>>>(w, bias, in_scale, wqp, bq, out_scalar);
    gemm_kernel<<<GRID, 256, 0, stream>>>(cx, wqp, bq, out, ntiles);
}